// Round 1
// 1236.448 us; speedup vs baseline: 1.4467x; 1.4467x over previous
//
#include <hip/hip_runtime.h>
#include <math.h>

#define HH 12
#define SS 2048
#define DM 768
#define DK 64

typedef _Float16 f16x8 __attribute__((ext_vector_type(8)));
typedef _Float16 f16x4 __attribute__((ext_vector_type(4)));
typedef float    f32x4 __attribute__((ext_vector_type(4)));

#define MFMA_F16(A, B, C) __builtin_amdgcn_mfma_f32_16x16x32_f16((A), (B), (C), 0, 0, 0)

// ---------------------------------------------------------------------------
// GEMM: C[M=4096, 768] = A[M,768] @ W[768,768] + bias
// fp32 VALU mainloop (unchanged from verified baseline). Epilogue by MODE:
//   MODE 0: plain fp32 [M,768]                       (final out)
//   MODE 1: head-split hi/lo fp16 planes [B,H,S,64]  (Q, K)
//   MODE 2: head-split TRANSPOSED hi/lo [B,H,64,S]   (V: PV B-operand layout)
// hi = fp16(v), lo = fp16(v - hi): split-fp16 so MFMA reaches fp32 accuracy.
// ---------------------------------------------------------------------------
template <int MODE>
__global__ __launch_bounds__(256) void gemm_bias_kernel(
        const float* __restrict__ A, const float* __restrict__ W,
        const float* __restrict__ bias, float* __restrict__ C,
        _Float16* __restrict__ Chi, _Float16* __restrict__ Clo)
{
    __shared__ float Ast[16][68];
    __shared__ float Bs[16][68];

    const int tid = threadIdx.x;
    const int tx = tid & 15, ty = tid >> 4;
    const int n0 = blockIdx.x * 64;
    const int m0 = blockIdx.y * 64;

    float acc[4][4] = {};

    for (int kt = 0; kt < 48; ++kt) {
        __syncthreads();
        #pragma unroll
        for (int it = 0; it < 4; ++it) {
            int idx = tid + it * 256;
            int r = idx >> 4, c = idx & 15;
            Ast[c][r] = A[(size_t)(m0 + r) * DM + kt * 16 + c];
        }
        {
            int r = tid >> 4, c = tid & 15;
            *(float4*)&Bs[r][c << 2] =
                *(const float4*)&W[(size_t)(kt * 16 + r) * DM + n0 + (c << 2)];
        }
        __syncthreads();

        #pragma unroll 4
        for (int kk = 0; kk < 16; ++kk) {
            float4 a4 = *(const float4*)&Ast[kk][ty << 2];
            float4 b4 = *(const float4*)&Bs[kk][tx << 2];
            float av[4] = {a4.x, a4.y, a4.z, a4.w};
            float bv[4] = {b4.x, b4.y, b4.z, b4.w};
            #pragma unroll
            for (int i = 0; i < 4; ++i)
                #pragma unroll
                for (int j = 0; j < 4; ++j)
                    acc[i][j] = fmaf(av[i], bv[j], acc[i][j]);
        }
    }

    const float4 bb4 = *(const float4*)&bias[n0 + (tx << 2)];
    const float bvv[4] = {bb4.x, bb4.y, bb4.z, bb4.w};

    if (MODE == 0) {
        #pragma unroll
        for (int i = 0; i < 4; ++i) {
            int m = m0 + ty * 4 + i;
            float4 o;
            o.x = acc[i][0] + bvv[0];
            o.y = acc[i][1] + bvv[1];
            o.z = acc[i][2] + bvv[2];
            o.w = acc[i][3] + bvv[3];
            *(float4*)&C[(size_t)m * DM + n0 + (tx << 2)] = o;
        }
    } else if (MODE == 1) {
        const int h = blockIdx.x;  // N-tile == head since DK == 64
        #pragma unroll
        for (int i = 0; i < 4; ++i) {
            int m = m0 + ty * 4 + i;
            int b_ = m >> 11, s_ = m & 2047;
            size_t base = (((size_t)(b_ * HH + h) * SS + s_) << 6) + (tx << 2);
            f16x4 hi, lo;
            #pragma unroll
            for (int j = 0; j < 4; ++j) {
                float v = acc[i][j] + bvv[j];
                _Float16 hv = (_Float16)v;
                hi[j] = hv;
                lo[j] = (_Float16)(v - (float)hv);
            }
            *(f16x4*)&Chi[base] = hi;
            *(f16x4*)&Clo[base] = lo;
        }
    } else {  // MODE 2: Vt[bh][dk][key], contiguous along key
        const int h  = blockIdx.x;
        const int m  = m0 + ty * 4;
        const int b_ = m >> 11;
        const int s_ = m & 2047;
        #pragma unroll
        for (int j = 0; j < 4; ++j) {
            int dk = (tx << 2) + j;
            size_t base = ((size_t)(b_ * HH + h) * DK + dk) * SS + s_;
            f16x4 hi, lo;
            #pragma unroll
            for (int i = 0; i < 4; ++i) {
                float v = acc[i][j] + bvv[j];
                _Float16 hv = (_Float16)v;
                hi[i] = hv;
                lo[i] = (_Float16)(v - (float)hv);
            }
            *(f16x4*)&Chi[base] = hi;
            *(f16x4*)&Clo[base] = lo;
        }
    }
}

// ---------------------------------------------------------------------------
// Fused attention, split-fp16 MFMA.
// Block = 4 waves, 64 queries (16 per wave). Per wave:
//   pass A: for all 2048 keys in 16-key tiles: s = QK^T via 6 MFMAs
//           (Qhi*Khi + Qlo*Khi + Qhi*Klo), lsum += exp(s/8)  (no max needed:
//           logits ~N(0,1), fp32 exp safe; identical to softmax analytically)
//   pass B: recompute s, p = exp(s/8)/l -> attnW; P transposed C->A layout
//           through per-wave LDS (x512 to stay clear of fp16 denorm floor);
//           O += P@V via 3 MFMAs per 16-dk tile against pre-transposed Vt.
// Fragment layouts (16x16x32, verified family): A/B lane = (l&15)=row/col,
// k = (l>>4)*8+j contiguous; C/D col = l&15, row = (l>>4)*4+reg.
// ---------------------------------------------------------------------------
__global__ __launch_bounds__(256) void attn_kernel(
        const _Float16* __restrict__ Qhi, const _Float16* __restrict__ Qlo,
        const _Float16* __restrict__ Khi, const _Float16* __restrict__ Klo,
        const _Float16* __restrict__ Vthi, const _Float16* __restrict__ Vtlo,
        float* __restrict__ attnW, float* __restrict__ ctx)
{
    __shared__ float Ps[4][16][34];   // per-wave P-transpose tile (+2 pad)

    const int tid  = threadIdx.x;
    const int wave = tid >> 6;
    const int lane = tid & 63;
    const int lrow = lane & 15;        // A/B fragment row (m or n)
    const int lk   = (lane >> 4) * 8;  // k-octet base within K=32
    const int grow = (lane >> 4) * 4;  // C/D fragment row base

    const int qt = blockIdx.x;         // 0..31
    const int bh = blockIdx.y;         // 0..23
    const int qw0 = qt * 64 + wave * 16;
    const size_t qkbase = (size_t)bh * SS * DK;  // halves, [bh][s][dk]
    const size_t vbase  = (size_t)bh * DK * SS;  // halves, [bh][dk][s]

    // Q fragments, reused across all key tiles and both passes
    f16x8 qhi[2], qlo[2];
    {
        const size_t qidx = qkbase + (size_t)(qw0 + lrow) * DK + lk;
        qhi[0] = *(const f16x8*)&Qhi[qidx];
        qhi[1] = *(const f16x8*)&Qhi[qidx + 32];
        qlo[0] = *(const f16x8*)&Qlo[qidx];
        qlo[1] = *(const f16x8*)&Qlo[qidx + 32];
    }

    // ---------------- pass A: row sums of exp ----------------
    float lsum[4] = {0.f, 0.f, 0.f, 0.f};
    #pragma unroll 2
    for (int kt = 0; kt < 128; ++kt) {
        const size_t kidx = qkbase + (size_t)(kt * 16 + lrow) * DK + lk;
        f16x8 khi0 = *(const f16x8*)&Khi[kidx];
        f16x8 khi1 = *(const f16x8*)&Khi[kidx + 32];
        f16x8 klo0 = *(const f16x8*)&Klo[kidx];
        f16x8 klo1 = *(const f16x8*)&Klo[kidx + 32];
        f32x4 acc = {0.f, 0.f, 0.f, 0.f};
        acc = MFMA_F16(qhi[0], khi0, acc);
        acc = MFMA_F16(qhi[1], khi1, acc);
        acc = MFMA_F16(qlo[0], khi0, acc);
        acc = MFMA_F16(qlo[1], khi1, acc);
        acc = MFMA_F16(qhi[0], klo0, acc);
        acc = MFMA_F16(qhi[1], klo1, acc);
        #pragma unroll
        for (int r = 0; r < 4; ++r)
            lsum[r] += __expf(acc[r] * 0.125f);
    }

    // reduce across the 16 lanes that share each row group (xor masks < 16)
    #pragma unroll
    for (int r = 0; r < 4; ++r) {
        lsum[r] += __shfl_xor(lsum[r], 1, 64);
        lsum[r] += __shfl_xor(lsum[r], 2, 64);
        lsum[r] += __shfl_xor(lsum[r], 4, 64);
        lsum[r] += __shfl_xor(lsum[r], 8, 64);
    }
    float rl[4];
    #pragma unroll
    for (int r = 0; r < 4; ++r) rl[r] = 1.0f / lsum[r];

    // ---------------- pass B: p-write + PV ----------------
    f32x4 Oacc[4];
    #pragma unroll
    for (int n = 0; n < 4; ++n) Oacc[n] = (f32x4){0.f, 0.f, 0.f, 0.f};

    float (*ps)[34] = Ps[wave];

    for (int kt = 0; kt < 64; ++kt) {           // 32 keys per iteration
        #pragma unroll
        for (int sub = 0; sub < 2; ++sub) {
            const int k16 = kt * 2 + sub;
            const size_t kidx = qkbase + (size_t)(k16 * 16 + lrow) * DK + lk;
            f16x8 khi0 = *(const f16x8*)&Khi[kidx];
            f16x8 khi1 = *(const f16x8*)&Khi[kidx + 32];
            f16x8 klo0 = *(const f16x8*)&Klo[kidx];
            f16x8 klo1 = *(const f16x8*)&Klo[kidx + 32];
            f32x4 acc = {0.f, 0.f, 0.f, 0.f};
            acc = MFMA_F16(qhi[0], khi0, acc);
            acc = MFMA_F16(qhi[1], khi1, acc);
            acc = MFMA_F16(qlo[0], khi0, acc);
            acc = MFMA_F16(qlo[1], khi1, acc);
            acc = MFMA_F16(qhi[0], klo0, acc);
            acc = MFMA_F16(qhi[1], klo1, acc);
            #pragma unroll
            for (int r = 0; r < 4; ++r) {
                float p = __expf(acc[r] * 0.125f) * rl[r];
                attnW[((size_t)bh * SS + qw0 + grow + r) * SS + k16 * 16 + lrow] = p;
                ps[grow + r][sub * 16 + lrow] = p * 512.0f;  // scale clear of fp16 denorms
            }
        }
        // wave-synchronous LDS transpose: C-layout -> A-layout (in-order DS pipe)
        float pf[8];
        #pragma unroll
        for (int j = 0; j < 8; ++j) pf[j] = ps[lrow][lk + j];
        f16x8 phi, plo;
        #pragma unroll
        for (int j = 0; j < 8; ++j) {
            _Float16 h = (_Float16)pf[j];
            phi[j] = h;
            plo[j] = (_Float16)(pf[j] - (float)h);
        }
        #pragma unroll
        for (int n = 0; n < 4; ++n) {
            const size_t vidx = vbase + (size_t)(n * 16 + lrow) * SS + kt * 32 + lk;
            f16x8 vhi = *(const f16x8*)&Vthi[vidx];
            f16x8 vlo = *(const f16x8*)&Vtlo[vidx];
            Oacc[n] = MFMA_F16(phi, vhi, Oacc[n]);
            Oacc[n] = MFMA_F16(plo, vhi, Oacc[n]);
            Oacc[n] = MFMA_F16(phi, vlo, Oacc[n]);
        }
    }

    // write ctx in [B,S,768] layout (undo the x512 P scaling)
    const int b_ = bh / HH, h_ = bh % HH;
    #pragma unroll
    for (int n = 0; n < 4; ++n)
        #pragma unroll
        for (int r = 0; r < 4; ++r) {
            int q = qw0 + grow + r;
            ctx[((size_t)b_ * SS + q) * DM + h_ * DK + n * 16 + lrow] =
                Oacc[n][r] * 0.001953125f;
        }
}

extern "C" void kernel_launch(void* const* d_in, const int* in_sizes, int n_in,
                              void* d_out, int out_size, void* d_ws, size_t ws_size,
                              hipStream_t stream) {
    const float* q   = (const float*)d_in[0];
    const float* k   = (const float*)d_in[1];
    const float* v   = (const float*)d_in[2];
    const float* w_q = (const float*)d_in[3];
    const float* b_q = (const float*)d_in[4];
    const float* w_k = (const float*)d_in[5];
    const float* b_k = (const float*)d_in[6];
    const float* w_v = (const float*)d_in[7];
    const float* b_v = (const float*)d_in[8];
    const float* w_o = (const float*)d_in[9];
    const float* b_o = (const float*)d_in[10];

    float* out   = (float*)d_out;                    // [2,2048,768]
    float* attnW = out + (size_t)2 * SS * DM;        // [2,12,2048,2048]

    // workspace: 6 half-planes of 3,145,728 halves + fp32 ctx = 48 MB total
    _Float16* wsh  = (_Float16*)d_ws;
    const size_t PL = (size_t)2 * HH * SS * DK;      // 3,145,728
    _Float16* Qhi  = wsh;
    _Float16* Qlo  = wsh + PL;
    _Float16* Khi  = wsh + 2 * PL;
    _Float16* Klo  = wsh + 3 * PL;
    _Float16* Vthi = wsh + 4 * PL;
    _Float16* Vtlo = wsh + 5 * PL;
    float* ctx     = (float*)(wsh + 6 * PL);         // [2,2048,768]

    dim3 gg(12, 64), blk(256);
    gemm_bias_kernel<1><<<gg, blk, 0, stream>>>(q, w_q, b_q, nullptr, Qhi, Qlo);
    gemm_bias_kernel<1><<<gg, blk, 0, stream>>>(k, w_k, b_k, nullptr, Khi, Klo);
    gemm_bias_kernel<2><<<gg, blk, 0, stream>>>(v, w_v, b_v, nullptr, Vthi, Vtlo);

    attn_kernel<<<dim3(32, 24), blk, 0, stream>>>(Qhi, Qlo, Khi, Klo, Vthi, Vtlo,
                                                  attnW, ctx);

    gemm_bias_kernel<0><<<gg, blk, 0, stream>>>(ctx, w_o, b_o, out, nullptr, nullptr);
}